// Round 6
// baseline (201.751 us; speedup 1.0000x reference)
//
#include <hip/hip_runtime.h>

typedef _Float16 f16;
typedef __attribute__((ext_vector_type(4))) _Float16 f16x4;
typedef __attribute__((ext_vector_type(8))) _Float16 f16x8;
typedef __attribute__((ext_vector_type(4))) float f32x4;

#define MM 2048
#define DD 256
#define LOG2E 1.44269504088896340736f

__device__ __forceinline__ void gload_lds16(const void* g, void* l) {
    __builtin_amdgcn_global_load_lds(
        (const __attribute__((address_space(1))) unsigned int*)g,
        (__attribute__((address_space(3))) unsigned int*)l, 16, 0, 0);
}
__device__ __forceinline__ f32x4 mfma16(f16x8 a, f16x8 b, f32x4 c) {
    return __builtin_amdgcn_mfma_f32_16x16x32_f16(a, b, c, 0, 0, 0);
}

// Prep (verified R1/R2/R5): memory f32 [2048][256] -> two fp16 copies, 16B-unit layouts.
// Kprep: per 32-row tile b: unit(u,kk) = memory[32b+kk][8u..8u+7]   (u=0..31, kk=0..31)
// VTprep: per 32-row tile b: unit(u,d)  = memory[32b+8u+e][d] e=0..7 (u=0..3,  d=0..255)
__global__ void prep_kernel(const float* __restrict__ mem,
                            f16* __restrict__ kprep, f16* __restrict__ vtprep) {
    int t = blockIdx.x * blockDim.x + threadIdx.x;
    if (t < 65536) {
        int b = t >> 10, r = t & 1023, u = r >> 5, kk = r & 31;
        const float* src = mem + (b * 32 + kk) * DD + u * 8;
        f16 o8[8];
#pragma unroll
        for (int e = 0; e < 8; ++e) o8[e] = (f16)src[e];
        *(f16x8*)(kprep + (size_t)t * 8) = *(f16x8*)o8;
    } else {
        int t2 = t - 65536;
        int b = t2 >> 10, r = t2 & 1023, u = r >> 8, d = r & 255;
        f16 o8[8];
#pragma unroll
        for (int e = 0; e < 8; ++e) o8[e] = (f16)mem[(b * 32 + u * 8 + e) * DD + d];
        *(f16x8*)(vtprep + (size_t)t2 * 8) = *(f16x8*)o8;
    }
}

// 512 blocks x 512 threads (8 waves x 16 q-rows). KV tile = 32, 64 iters.
// Counted-vmcnt raw-barrier pipeline: K staged 2 tiles ahead, VT 1 ahead;
// PV deferred one iteration so softmax VALU overlaps the PV MFMA drain.
// Ledger (per wave, 2 gload-instr per STAGE): entering barrier A: outstanding
// {K(b) [E(b-2)], VT(b-1) [B(b-1)], K(b+1) [E(b-1)]} = 6 -> vmcnt(2) drains
// K(b),VT(b-1), leaves K(b+1) in flight across the barrier.
__launch_bounds__(512, 2)
__global__ void attn_kernel(const float* __restrict__ q,
                            const f16* __restrict__ kprep,
                            const f16* __restrict__ vtprep,
                            float* __restrict__ out) {
    __shared__ __align__(16) f16 klds[2][8192];   // 32KB K tiles, unit [u=32][kk=32]
    __shared__ __align__(16) f16 vtlds[2][8192];  // 32KB VT tiles, unit [u=4][d=256]
    __shared__ __align__(16) f16 plds[8][16 * 40];  // per-wave P, row stride 40 f16

    const int tid = threadIdx.x;
    const int w = __builtin_amdgcn_readfirstlane(tid >> 6);
    const int lane = tid & 63;
    const int g = lane >> 4;
    const int l15 = lane & 15;
    const int q0 = blockIdx.x * 128 + w * 16;

    // Q A-frags: qf[dc] lane(g,l15) elem j = Q[q0+l15][32dc+8g+j]
    f16x8 qf[8];
#pragma unroll
    for (int dc = 0; dc < 8; ++dc) {
        const float* src = q + (size_t)(q0 + l15) * DD + dc * 32 + g * 8;
        float4 a = *(const float4*)src;
        float4 b2 = *(const float4*)(src + 4);
        f16 t8[8] = {(f16)a.x, (f16)a.y, (f16)a.z, (f16)a.w,
                     (f16)b2.x, (f16)b2.y, (f16)b2.z, (f16)b2.w};
        qf[dc] = *(f16x8*)t8;
    }

    f32x4 o[16];
#pragma unroll
    for (int dt = 0; dt < 16; ++dt) o[dt] = (f32x4){0.f, 0.f, 0.f, 0.f};
    f32x4 lsum = (f32x4){0.f, 0.f, 0.f, 0.f};
    float mrun = -1e30f;

    f16x8 ones;
#pragma unroll
    for (int e = 0; e < 8; ++e) ones[e] = (f16)1.0f;

    f16* pw = plds[w];

    // Each STAGE = 2 gload_lds instr/thread (512 thr x 2 x 16B = 16KB tile).
#define STAGE_K(b_, c_)                                                   \
    do {                                                                  \
        const f16* s_ = kprep + (size_t)(b_)*8192;                        \
        _Pragma("unroll")                                                 \
        for (int i_ = 0; i_ < 2; ++i_)                                    \
            gload_lds16(s_ + i_ * 4096 + w * 512 + lane * 8,              \
                        &klds[c_][i_ * 4096 + w * 512]);                  \
    } while (0)
#define STAGE_VT(b_, c_)                                                  \
    do {                                                                  \
        const f16* s_ = vtprep + (size_t)(b_)*8192;                       \
        _Pragma("unroll")                                                 \
        for (int i_ = 0; i_ < 2; ++i_)                                    \
            gload_lds16(s_ + i_ * 4096 + w * 512 + lane * 8,              \
                        &vtlds[c_][i_ * 4096 + w * 512]);                 \
    } while (0)

    // Clean vmcnt ledger, then prologue: K(0), K(1) -> 4 outstanding.
    asm volatile("s_waitcnt vmcnt(0)" ::: "memory");
    __builtin_amdgcn_sched_barrier(0);
    STAGE_K(0, 0);
    STAGE_K(1, 1);

    for (int b = 0; b < 64; ++b) {
        const int c = b & 1;
        // A: K(b) + VT(b-1) guaranteed resident; K(b+1) stays in flight.
        asm volatile("s_waitcnt vmcnt(2)" ::: "memory");
        __builtin_amdgcn_s_barrier();
        __builtin_amdgcn_sched_barrier(0);
        // B: VT(b) -> vtlds[c], consumed by PV at iter b+1.
        STAGE_VT(b, c);

        // C: S^T = K Q^T on klds[c]: s0[rr]=S[k=4g+rr][q=l15], s1: k=16+4g+rr
        f32x4 s0 = (f32x4){0.f, 0.f, 0.f, 0.f};
        f32x4 s1 = (f32x4){0.f, 0.f, 0.f, 0.f};
        __builtin_amdgcn_s_setprio(1);
#pragma unroll
        for (int dc = 0; dc < 8; ++dc) {
            f16x8 bk0 = *(const f16x8*)(&klds[c][((dc * 4 + g) * 32 + l15) * 8]);
            f16x8 bk1 = *(const f16x8*)(&klds[c][((dc * 4 + g) * 32 + 16 + l15) * 8]);
            s0 = mfma16(bk0, qf[dc], s0);
            s1 = mfma16(bk1, qf[dc], s1);
        }
        __builtin_amdgcn_s_setprio(0);

        // D: all waves done reading klds[c] -> safe to overwrite.
        __builtin_amdgcn_sched_barrier(0);
        __builtin_amdgcn_s_barrier();
        __builtin_amdgcn_sched_barrier(0);
        // E: K(b+2) -> klds[c] (wrap at tail keeps vmcnt counts uniform;
        //    the wrapped tiles are never read).
        STAGE_K((b + 2) & 63, c);

        // F1: deferred PV(b-1) + lsum; softmax(b) VALU below overlaps its drain.
        if (b) {
            f16x8 pa = *(const f16x8*)(pw + l15 * 40 + g * 8);
            __builtin_amdgcn_s_setprio(1);
#pragma unroll
            for (int dt = 0; dt < 16; ++dt) {
                f16x8 bv = *(const f16x8*)(&vtlds[c ^ 1][(g * 256 + dt * 16 + l15) * 8]);
                o[dt] = mfma16(pa, bv, o[dt]);
            }
            lsum = mfma16(pa, ones, lsum);
            __builtin_amdgcn_s_setprio(0);
        }

        // F2: online softmax (base-2), defer-max; rescale stalls on PV drain
        // only on the rare trigger iterations.
        float a0 = fmaxf(fmaxf(s0[0], s0[1]), fmaxf(s0[2], s0[3]));
        float a1 = fmaxf(fmaxf(s1[0], s1[1]), fmaxf(s1[2], s1[3]));
        float sm = fmaxf(a0, a1) * LOG2E;
        if (__any(sm > mrun + 8.0f)) {
            sm = fmaxf(sm, __shfl_xor(sm, 16));
            sm = fmaxf(sm, __shfl_xor(sm, 32));
            const float mnew = fmaxf(mrun, sm);
            const float fct = __builtin_amdgcn_exp2f(mrun - mnew);
            mrun = mnew;
            const float f0 = __shfl(fct, 4 * g + 0, 16);
            const float f1 = __shfl(fct, 4 * g + 1, 16);
            const float f2 = __shfl(fct, 4 * g + 2, 16);
            const float f3 = __shfl(fct, 4 * g + 3, 16);
#pragma unroll
            for (int dt = 0; dt < 16; ++dt) {
                o[dt][0] *= f0; o[dt][1] *= f1;
                o[dt][2] *= f2; o[dt][3] *= f3;
            }
            lsum[0] *= f0; lsum[1] *= f1; lsum[2] *= f2; lsum[3] *= f3;
        }
        float pr[8];
#pragma unroll
        for (int rr = 0; rr < 4; ++rr) {
            pr[rr] = __builtin_amdgcn_exp2f(__builtin_fmaf(s0[rr], LOG2E, -mrun));
            pr[4 + rr] = __builtin_amdgcn_exp2f(__builtin_fmaf(s1[rr], LOG2E, -mrun));
        }
        // P(b)[q=l15][16kt+4g+rr] -> per-wave LDS (read next iter; write after
        // this iter's pa read, so no overwrite hazard).
        f16x4 p0 = {(f16)pr[0], (f16)pr[1], (f16)pr[2], (f16)pr[3]};
        f16x4 p1 = {(f16)pr[4], (f16)pr[5], (f16)pr[6], (f16)pr[7]};
        *(f16x4*)(pw + l15 * 40 + 4 * g) = p0;
        *(f16x4*)(pw + l15 * 40 + 16 + 4 * g) = p1;
    }

    // Epilogue: full drain (also retires the wrapped K stages -- in-flight
    // LDS-DMA past endpgm would corrupt the next block's LDS), then PV(63).
    asm volatile("s_waitcnt vmcnt(0)" ::: "memory");
    __builtin_amdgcn_s_barrier();
    __builtin_amdgcn_sched_barrier(0);
    {
        f16x8 pa = *(const f16x8*)(pw + l15 * 40 + g * 8);
#pragma unroll
        for (int dt = 0; dt < 16; ++dt) {
            f16x8 bv = *(const f16x8*)(&vtlds[1][(g * 256 + dt * 16 + l15) * 8]);
            o[dt] = mfma16(pa, bv, o[dt]);
        }
        lsum = mfma16(pa, ones, lsum);
    }

    // Store: O rows are q0+4g+rr; lsum[rr] is that row's denominator.
    float inv0 = 1.0f / lsum[0], inv1 = 1.0f / lsum[1];
    float inv2 = 1.0f / lsum[2], inv3 = 1.0f / lsum[3];
#pragma unroll
    for (int dt = 0; dt < 16; ++dt) {
        const size_t base = (size_t)(q0 + 4 * g) * DD + dt * 16 + l15;
        out[base] = o[dt][0] * inv0;
        out[base + DD] = o[dt][1] * inv1;
        out[base + 2 * DD] = o[dt][2] * inv2;
        out[base + 3 * DD] = o[dt][3] * inv3;
    }
}

extern "C" void kernel_launch(void* const* d_in, const int* in_sizes, int n_in,
                              void* d_out, int out_size, void* d_ws, size_t ws_size,
                              hipStream_t stream) {
    const float* memory = (const float*)d_in[0];
    const float* query = (const float*)d_in[1];
    float* out = (float*)d_out;
    f16* kprep = (f16*)d_ws;                 // 1 MB
    f16* vtprep = kprep + (size_t)MM * DD;   // 1 MB
    prep_kernel<<<512, 256, 0, stream>>>(memory, kprep, vtprep);
    attn_kernel<<<512, 512, 0, stream>>>(query, kprep, vtprep, out);
}

// Round 8
// 158.204 us; speedup vs baseline: 1.2753x; 1.2753x over previous
//
#include <hip/hip_runtime.h>

typedef _Float16 f16;
typedef __attribute__((ext_vector_type(8))) _Float16 f16x8;
typedef __attribute__((ext_vector_type(4))) float f32x4;
typedef __attribute__((ext_vector_type(16))) float f32x16;
typedef __attribute__((ext_vector_type(4))) unsigned u32x4;

#define MM 2048
#define DD 256
#define LOG2E 1.44269504088896340736f

__device__ __forceinline__ void gload_lds16(const void* g, void* l) {
    __builtin_amdgcn_global_load_lds(
        (const __attribute__((address_space(1))) unsigned int*)g,
        (__attribute__((address_space(3))) unsigned int*)l, 16, 0, 0);
}
__device__ __forceinline__ f32x16 mfma32(f16x8 a, f16x8 b, f32x16 c) {
    return __builtin_amdgcn_mfma_f32_32x32x16_f16(a, b, c, 0, 0, 0);
}
// v_permlane32_swap_b32 a,b:  a' = {a.lo32lanes, b.lo32lanes}, b' = {a.hi, b.hi}
__device__ __forceinline__ void plswap(unsigned& a, unsigned& b) {
    asm volatile("v_permlane32_swap_b32 %0, %1" : "+v"(a), "+v"(b));
}
__device__ __forceinline__ unsigned pk2(float a, float b) {
    // builtin returns __fp16 ext_vector(2); bit-identical to 32-bit payload
    return __builtin_bit_cast(unsigned, __builtin_amdgcn_cvt_pkrtz(a, b));
}

// Prep (verified R2/R5): memory f32 [2048][256] -> two fp16 copies, 16B-unit layouts.
// Kprep: per 32-row tile b: unit(d8,k) = memory[32b+k][8*d8..8*d8+7]   (d8=0..31, k=0..31)
// VTprep: per 32-row tile b: unit(kg,d) = memory[32b+8kg+e][d], e=0..7 (kg=0..3, d=0..255)
__global__ void prep_kernel(const float* __restrict__ mem,
                            f16* __restrict__ kprep, f16* __restrict__ vtprep) {
    int t = blockIdx.x * blockDim.x + threadIdx.x;
    if (t < 65536) {
        int b = t >> 10, r = t & 1023, u = r >> 5, kk = r & 31;
        const float* src = mem + (b * 32 + kk) * DD + u * 8;
        f16 o8[8];
#pragma unroll
        for (int e = 0; e < 8; ++e) o8[e] = (f16)src[e];
        *(f16x8*)(kprep + (size_t)t * 8) = *(f16x8*)o8;
    } else {
        int t2 = t - 65536;
        int b = t2 >> 10, r = t2 & 1023, u = r >> 8, d = r & 255;
        f16 o8[8];
#pragma unroll
        for (int e = 0; e < 8; ++e) o8[e] = (f16)mem[(b * 32 + u * 8 + e) * DD + d];
        *(f16x8*)(vtprep + (size_t)t2 * 8) = *(f16x8*)o8;
    }
}

// 512 blocks x 256 threads (4 waves x 32 q-rows). KV tile = 32, 64 iters.
// 32x32x16 MFMAs; S^T/O via swapped ops so q=lane&31 for softmax; P entirely
// in registers via cvt_pkrtz + permlane32_swap; lsum in VALU; defer-max.
// LDS = K dbuf 32K + VT dbuf 32K = 64 KB -> 2 blocks/CU.
__launch_bounds__(256, 2)
__global__ void attn_kernel(const float* __restrict__ q,
                            const f16* __restrict__ kprep,
                            const f16* __restrict__ vtprep,
                            float* __restrict__ out) {
    __shared__ __align__(16) f16 klds[2][8192];
    __shared__ __align__(16) f16 vtlds[2][8192];

    const int tid = threadIdx.x;
    const int w = __builtin_amdgcn_readfirstlane(tid >> 6);
    const int lane = tid & 63;
    const int h = lane >> 5;     // half-wave
    const int l31 = lane & 31;
    const int q0 = blockIdx.x * 128 + w * 32;

    // Q B-frags: qf[s] lane(h,l31) elem j = Q[q0+l31][16s+8h+j]  (col=q=l31)
    f16x8 qf[16];
#pragma unroll
    for (int s = 0; s < 16; ++s) {
        const float* src = q + (size_t)(q0 + l31) * DD + s * 16 + h * 8;
        float4 a = *(const float4*)src;
        float4 b2 = *(const float4*)(src + 4);
        f16 t8[8] = {(f16)a.x, (f16)a.y, (f16)a.z, (f16)a.w,
                     (f16)b2.x, (f16)b2.y, (f16)b2.z, (f16)b2.w};
        qf[s] = *(f16x8*)t8;
    }

    f32x16 o[8];
#pragma unroll
    for (int dt = 0; dt < 8; ++dt) o[dt] = (f32x16)(0.f);
    float lpart = 0.f, mrun = -1e30f;

#define STAGE_K(b_, c_)                                                   \
    do {                                                                  \
        const f16* s_ = kprep + (size_t)(b_)*8192;                        \
        _Pragma("unroll")                                                 \
        for (int i_ = 0; i_ < 4; ++i_)                                    \
            gload_lds16(s_ + i_ * 2048 + w * 512 + lane * 8,              \
                        &klds[c_][i_ * 2048 + w * 512]);                  \
    } while (0)
#define STAGE_VT(b_, c_)                                                  \
    do {                                                                  \
        const f16* s_ = vtprep + (size_t)(b_)*8192;                       \
        _Pragma("unroll")                                                 \
        for (int i_ = 0; i_ < 4; ++i_)                                    \
            gload_lds16(s_ + i_ * 2048 + w * 512 + lane * 8,              \
                        &vtlds[c_][i_ * 2048 + w * 512]);                 \
    } while (0)

    STAGE_K(0, 0);
    STAGE_VT(0, 0);

    for (int b = 0; b < 64; ++b) {
        const int c = b & 1;
        __syncthreads();  // drains vmcnt: K(b)/VT(b) resident; buf c^1 free
        if (b < 63) { STAGE_K(b + 1, c ^ 1); STAGE_VT(b + 1, c ^ 1); }

        // ---- S^T = K Q^T (32k x 32q, one 32x32 tile, 16 chained MFMAs)
        // C-layout: col=q=l31, row=k=(r&3)+8*(r>>2)+4*h
        f32x16 s = (f32x16)(0.f);
        __builtin_amdgcn_s_setprio(1);
#pragma unroll
        for (int st = 0; st < 16; ++st) {
            f16x8 ak = *(const f16x8*)(&klds[c][((2 * st + h) * 32 + l31) * 8]);
            s = mfma32(ak, qf[st], s);
        }
        __builtin_amdgcn_s_setprio(0);

        // ---- softmax (base-2), defer-max; q is lane-local -> per-lane reduce
        float sm = s[0];
#pragma unroll
        for (int r = 1; r < 16; ++r) sm = fmaxf(sm, s[r]);
        sm *= LOG2E;
        if (__any(sm > mrun + 8.0f)) {
            sm = fmaxf(sm, __shfl_xor(sm, 32));  // combine h-halves (same q)
            const float mnew = fmaxf(mrun, sm);
            const float fct = __builtin_amdgcn_exp2f(mrun - mnew);
            mrun = mnew;
            lpart *= fct;
            // O rows are q=(r&3)+8(r>>2)+4h -> per-reg factor via width-32 shfl
            float fr[16];
#pragma unroll
            for (int r = 0; r < 16; ++r)
                fr[r] = __shfl(fct, (r & 3) + 8 * (r >> 2) + 4 * h, 32);
#pragma unroll
            for (int dt = 0; dt < 8; ++dt)
#pragma unroll
                for (int r = 0; r < 16; ++r) o[dt][r] *= fr[r];
        }
        float p[16];
        float rs = 0.f;
#pragma unroll
        for (int r = 0; r < 16; ++r) {
            p[r] = __builtin_amdgcn_exp2f(__builtin_fmaf(s[r], LOG2E, -mrun));
            rs += p[r];
        }
        lpart += rs;  // own-half partial; partner-combined in epilogue

        // ---- P -> PV A-frags entirely in registers.
        // p[r] holds P[k=(r&3)+8(r>>2)+4h][q=l31]. Pack k-pairs:
        unsigned c0 = pk2(p[0], p[1]),  c1 = pk2(p[2], p[3]);    // k=4h+{0..3}
        unsigned c2 = pk2(p[4], p[5]),  c3 = pk2(p[6], p[7]);    // k=8+4h+{0..3}
        unsigned c4 = pk2(p[8], p[9]),  c5 = pk2(p[10], p[11]);  // k=16+4h+{0..3}
        unsigned c6 = pk2(p[12], p[13]), c7 = pk2(p[14], p[15]); // k=24+4h+{0..3}
        plswap(c0, c2); plswap(c1, c3);  // -> pa0 covers k=0..15 per A-slot map
        plswap(c4, c6); plswap(c5, c7);  // -> pa1 covers k=16..31
        u32x4 pk0 = {c0, c1, c2, c3};
        u32x4 pk1 = {c4, c5, c6, c7};
        f16x8 pa0 = __builtin_bit_cast(f16x8, pk0);
        f16x8 pa1 = __builtin_bit_cast(f16x8, pk1);

        // ---- O += P V  (A=P: row=q, k; B=VT: col=d=l31, k=16t+8h+j)
        __builtin_amdgcn_s_setprio(1);
#pragma unroll
        for (int dt = 0; dt < 8; ++dt) {
            f16x8 v0 = *(const f16x8*)(&vtlds[c][((0 + h) * 256 + dt * 32 + l31) * 8]);
            f16x8 v1 = *(const f16x8*)(&vtlds[c][((2 + h) * 256 + dt * 32 + l31) * 8]);
            o[dt] = mfma32(pa0, v0, o[dt]);
            o[dt] = mfma32(pa1, v1, o[dt]);
        }
        __builtin_amdgcn_s_setprio(0);
    }

    // ---- epilogue: combine l across h-halves, normalize, store.
    // O C-layout: col=d=l31 (within 32-col d-tile dt), row=q=(r&3)+8(r>>2)+4h.
    const float ltot = lpart + __shfl_xor(lpart, 32);
    const float inv = 1.0f / ltot;  // per q=l31
    float invr[16];
#pragma unroll
    for (int r = 0; r < 16; ++r)
        invr[r] = __shfl(inv, (r & 3) + 8 * (r >> 2) + 4 * h, 32);
#pragma unroll
    for (int dt = 0; dt < 8; ++dt)
#pragma unroll
        for (int r = 0; r < 16; ++r) {
            const int qrow = (r & 3) + 8 * (r >> 2) + 4 * h;
            out[(size_t)(q0 + qrow) * DD + dt * 32 + l31] = o[dt][r] * invr[r];
        }
}

extern "C" void kernel_launch(void* const* d_in, const int* in_sizes, int n_in,
                              void* d_out, int out_size, void* d_ws, size_t ws_size,
                              hipStream_t stream) {
    const float* memory = (const float*)d_in[0];
    const float* query = (const float*)d_in[1];
    float* out = (float*)d_out;
    f16* kprep = (f16*)d_ws;                 // 1 MB
    f16* vtprep = kprep + (size_t)MM * DD;   // 1 MB
    prep_kernel<<<512, 256, 0, stream>>>(memory, kprep, vtprep);
    attn_kernel<<<512, 256, 0, stream>>>(query, kprep, vtprep, out);
}